// Round 5
// baseline (550.750 us; speedup 1.0000x reference)
//
#include <hip/hip_runtime.h>
#include <cstdint>
#include <math.h>

// Problem constants: B=32, TXT_T=256, MEL_T=1600, N_MEL=40
#define BB   32
#define LLEN 256
#define TLEN 1600
#define NC   40
#define NEGPADF (-1.0e12f)
#define NEGPADD (-1.0e12)
#define NBB   16            // DP columns per window (both sides; R11's NBA=32 regressed)
#define SUBB  8             // columns per producer sub-batch
#define NPROD 4             // producer waves
#define NBUF  3             // LDS column buffers (store-2-ahead)

#define LOG2E_F 1.4426950408889634f
#define LN2_F   0.6931471805599453f
#define C7F     1.4426950408889634e-7f  // 1e-7*log2e, folded into staged alpha lp

// Output layout (floats): mdn_loss[32] | alignment[32*1600*256] | lp[32*256*1600]
#define OFF_ALIGN 32
#define OFF_LP    (32 + (size_t)BB * TLEN * LLEN)

// Workspace (bytes): Ad double[32*256*80] | Kcd double[32*256] | lpTh float[32*1600*256]
#define WSB_A    0
#define WSB_KC   (WSB_A + (size_t)BB * LLEN * 80 * 8)
#define WSB_LPT  (WSB_KC + (size_t)BB * LLEN * 8)

__device__ __forceinline__ int imin(int a, int b) { return a < b ? a : b; }

#define WAIT_LGKM0 0xC07F   // lgkmcnt(0) only, vmcnt untouched (validated R2-R6)

// DPP wave-rotate-right-1: lane i <- lane i-1, lane 0 <- lane 63. VALU-only.
__device__ __forceinline__ int rot1_i32(int x) {
  return __builtin_amdgcn_mov_dpp(x, 0x13C /*wave_ror:1*/, 0xF, 0xF, true);
}
__device__ __forceinline__ float rot1_f32(float x) {
  return __int_as_float(rot1_i32(__float_as_int(x)));
}
__device__ __forceinline__ double rot1_f64(double x) {
  long long v = __double_as_longlong(x);
  int lo = rot1_i32((int)(v & 0xffffffffLL));
  int hi = rot1_i32((int)(v >> 32));
  return __longlong_as_double(((long long)hi << 32) | (unsigned long long)(unsigned int)lo);
}

// ---------------------------------------------------------------------------
// K0 (f64) [validated R2]
// ---------------------------------------------------------------------------
__global__ __launch_bounds__(256) void prep_kernel(
    const float* __restrict__ mu_logvar, double* __restrict__ A, double* __restrict__ Kc) {
  int row = blockIdx.x * 4 + (threadIdx.x >> 6);   // b*256 + l
  int lane = threadIdx.x & 63;
  const float* src = mu_logvar + (size_t)row * (2 * NC);
  double mu = 0.0, lv = 0.0, iv = 0.0, part = 0.0;
  if (lane < NC) {
    mu = (double)src[lane];
    lv = (double)src[NC + lane];
    iv = exp(-lv);
    part = mu * mu * iv + lv;
  }
  for (int m = 1; m < 64; m <<= 1) part += __shfl_xor(part, m, 64);
  const double s = -0.5 / (double)NC;
  if (lane < NC) {
    A[(size_t)row * 80 + lane]      = s * iv;
    A[(size_t)row * 80 + NC + lane] = (1.0 / (double)NC) * mu * iv;
  }
  if (lane == 0) Kc[row] = s * part;
}

// ---------------------------------------------------------------------------
// K1 (f64) [validated R2/R3/R5/R6 math]: lp + hi/lo transposed copies.
// ---------------------------------------------------------------------------
__global__ __launch_bounds__(128) void lp_kernel(
    const float* __restrict__ z, const double* __restrict__ A,
    const double* __restrict__ Kc, float* __restrict__ out,
    float* __restrict__ lpTh) {
  int b  = blockIdx.z;
  int l0 = blockIdx.y * 32;
  int t0 = blockIdx.x * 128;
  int tid = threadIdx.x;
  int t = t0 + tid;
  int tv = imin(t, TLEN - 1);
  bool act = (t < TLEN);

  float* lp_out = out + OFF_LP;
  float* loS    = out + OFF_ALIGN;   // lo scratch [b][t][l], zeroed by dp tail

  float zr[NC];
  const float* zb = z + (size_t)b * NC * TLEN;
  #pragma unroll
  for (int c = 0; c < NC; ++c) zr[c] = zb[(size_t)c * TLEN + tv];

  __shared__ __align__(16) double tile[128][17];
  const double* Ab = A + ((size_t)b * LLEN + l0) * 80;
  const double* Kb = Kc + (size_t)b * LLEN + l0;

  for (int g = 0; g < 2; ++g) {
    for (int j16 = 0; j16 < 16; ++j16) {
      int j = g * 16 + j16;
      const double* Ar = Ab + (size_t)j * 80;      // wave-uniform -> s_load
      double a0 = Kb[j], a1 = 0.0, a2 = 0.0, a3 = 0.0;
      #pragma unroll
      for (int c = 0; c < NC; c += 2) {
        double z0 = (double)zr[c], z1 = (double)zr[c + 1];
        a0 = fma(Ar[c],          z0 * z0, a0);
        a1 = fma(Ar[NC + c],     z0,      a1);
        a2 = fma(Ar[c + 1],      z1 * z1, a2);
        a3 = fma(Ar[NC + c + 1], z1,      a3);
      }
      double accd = (a0 + a2) + (a1 + a3);
      if (act) lp_out[((size_t)b * LLEN + l0 + j) * TLEN + t] = (float)accd;
      tile[tid][j16] = accd;
    }
    __syncthreads();
    #pragma unroll
    for (int p = 0; p < 4; ++p) {
      int idx = p * 128 + tid;
      int r = idx >> 2, c4 = idx & 3;
      int tr = t0 + r;
      if (tr < TLEN) {
        float h[4], lo[4];
        #pragma unroll
        for (int i = 0; i < 4; ++i) {
          double d = tile[r][c4 * 4 + i];
          float hh = (float)d;
          h[i] = hh;
          lo[i] = (float)(d - (double)hh);
        }
        size_t base = ((size_t)b * TLEN + tr) * LLEN + l0 + g * 16 + c4 * 4;
        *(float4*)(lpTh + base) = make_float4(h[0], h[1], h[2], h[3]);
        *(float4*)(loS + base)  = make_float4(lo[0], lo[1], lo[2], lo[3]);
      }
    }
    __syncthreads();
  }
}

// ---------------------------------------------------------------------------
// K2: DP, 64 blocks x 320 threads (1 consumer + 4 producer waves).
// R12: BARRIER-FREE window sync. s_barrier rendezvous (5 waves, ~100/block)
// replaced by LDS flags:
//  - prodSb[q]: sub-batches stored by producer q (plain write after lgkm
//    drain). Consumer gate for window w: min_q(q + 4*prodSb[q]) >= 2(w+2)
//    (all sb of windows <= w+1 stored). Normally satisfied on first poll.
//  - consW: windows completed by consumer. Producer writing window u waits
//    consW >= u-2 (s_sleep poll) so it never touches a buffer the consumer
//    still reads (consumer at w reads w%3,(w+1)%3; producer writes (w+2)%3).
// Deadlock-free: the producer the consumer waits on has u <= w+2, so its
// throttle consW >= u-2 is already satisfied by consW = w.
// Zero-fill: producer visiting window u zeroes cols of window u-2 (safe: all
// loads of those cols retired before consW reached u-2); tail covers windows
// nint-2, nint-1 and the [16*nint, 1600) remainder after the loop.
// Everything else (register-ring consumers, store-2-ahead, f64 beta math,
// Dbits/backtrack, fused scatter) = validated R9 code.
// ---------------------------------------------------------------------------
__global__ __launch_bounds__(320, 1) void dp_kernel(
    const float* __restrict__ lpTh, const float* outR,
    const int* __restrict__ tlen, const int* __restrict__ mlen,
    float* __restrict__ out) {
  int bid = blockIdx.x;
  bool is_beta = (bid >= BB);
  int b = is_beta ? bid - BB : bid;
  int tid = threadIdx.x;
  int lane = tid & 63;
  int wv = tid >> 6;                   // 0 = consumer, 1..4 = producers
  int tl = tlen[b];
  int ml = mlen[b];
  const float* lpb = lpTh + (size_t)b * TLEN * LLEN;
  const float* lob = outR + OFF_ALIGN + (size_t)b * TLEN * LLEN;
  float* al = out + OFF_ALIGN + (size_t)b * TLEN * LLEN;
  int nint = (ml - 2 + NBB) / NBB;     // windows of 16 steps (nint >= 50)
  int nsb  = 2 * nint;                 // sub-batch sb covers cols 1+8sb..8sb+8

  __shared__ __align__(16) double bufd[NBUF][NBB][4][64];   // beta cols, 96 KB
  __shared__ uint32_t Dbits[LLEN][TLEN / 32];               // 51.2 KB
  __shared__ int pathL[TLEN];                               // 6.4 KB
  __shared__ int prodSb_s[NPROD];                           // producer progress
  __shared__ int consW_s;                                   // consumer progress
  // alpha aliases bufd: 3 bufs x 16 cols x 4 planes x 64 lanes f32 = 48 KB
  float* bufaF = (float*)&bufd[0][0][0][0];

  if (tid < NPROD) prodSb_s[tid] = 0;
  if (tid == NPROD) consW_s = 0;
  __syncthreads();                     // flags visible to all waves

  if (wv >= 1) {
    // =================== producers (barrier-free) ==========================
    int q = wv - 1;
    const float* ph = lpb + 4 * lane;
    const float* pl = lob + 4 * lane;
    float4 vh[SUBB], vl[SUBB];
    float4 z4 = make_float4(0.f, 0.f, 0.f, 0.f);
    int myCnt = 0;
    if (!is_beta) {
      auto issueA = [&](int sb) {
        #pragma unroll
        for (int j = 0; j < SUBB; ++j) {
          int c = imin(1 + SUBB * sb + j, TLEN - 1);
          vh[j] = *(const float4*)(ph + (size_t)c * LLEN);
        }
      };
      auto storeA = [&](int sb) {
        int s  = (sb >> 1) % NBUF;
        int jb = (sb & 1) * SUBB;
        #pragma unroll
        for (int j = 0; j < SUBB; ++j) {
          int off = ((s * NBB + jb + j) * 4) * 64 + lane;
          bufaF[off]       = fmaf(vh[j].x, LOG2E_F, C7F);
          bufaF[off + 64]  = fmaf(vh[j].y, LOG2E_F, C7F);
          bufaF[off + 128] = fmaf(vh[j].z, LOG2E_F, C7F);
          bufaF[off + 192] = fmaf(vh[j].w, LOG2E_F, C7F);
        }
      };
      if (q < nsb) issueA(q);
      for (int sb = q; sb < nsb; sb += 4) {
        int u = sb >> 1;
        if (u >= 3) {
          while (*(volatile int*)&consW_s < u - 2) __builtin_amdgcn_s_sleep(2);
        }
        asm volatile("" ::: "memory");
        storeA(sb);                    // implicit vmcnt wait: only own loads out
        asm volatile("" ::: "memory");
        __builtin_amdgcn_s_waitcnt(WAIT_LGKM0);   // drain ds_writes
        ++myCnt;
        if (lane == 0) *(volatile int*)&prodSb_s[q] = myCnt;
        asm volatile("" ::: "memory");
        if (sb + 4 < nsb) issueA(sb + 4);
      }
    } else {
      auto issueB = [&](int sb) {
        #pragma unroll
        for (int j = 0; j < SUBB; ++j) {
          int c = imin(1 + SUBB * sb + j, TLEN - 1);
          vh[j] = *(const float4*)(ph + (size_t)c * LLEN);
          vl[j] = *(const float4*)(pl + (size_t)c * LLEN);
        }
      };
      auto storeB = [&](int sb) {
        int s  = (sb >> 1) % NBUF;
        int jb = (sb & 1) * SUBB;
        #pragma unroll
        for (int j = 0; j < SUBB; ++j) {
          bufd[s][jb + j][0][lane] = (double)vh[j].x + (double)vl[j].x;
          bufd[s][jb + j][1][lane] = (double)vh[j].y + (double)vl[j].y;
          bufd[s][jb + j][2][lane] = (double)vh[j].z + (double)vl[j].z;
          bufd[s][jb + j][3][lane] = (double)vh[j].w + (double)vl[j].w;
        }
      };
      if (q < nsb) issueB(q);
      for (int sb = q; sb < nsb; sb += 4) {
        int u = sb >> 1;
        if (u >= 3) {
          while (*(volatile int*)&consW_s < u - 2) __builtin_amdgcn_s_sleep(2);
        }
        asm volatile("" ::: "memory");
        storeB(sb);                    // implicit vmcnt wait: only own loads out
        asm volatile("" ::: "memory");
        __builtin_amdgcn_s_waitcnt(WAIT_LGKM0);   // drain ds_writes
        ++myCnt;
        if (lane == 0) *(volatile int*)&prodSb_s[q] = myCnt;
        asm volatile("" ::: "memory");
        if (sb + 4 < nsb) issueB(sb + 4);
        // zero-fill cols of window u-2 (8 cols per producer; pair parity(u))
        if (u >= 2) {
          int zc = NBB * (u - 2) + 8 * (q & 1);
          float* az = al + (size_t)zc * LLEN + 4 * lane;
          #pragma unroll
          for (int k = 0; k < 8; ++k) *(float4*)(az + (size_t)k * LLEN) = z4;
        }
      }
      // tail zero: windows nint-2, nint-1 and cols [16*nint, 1600).
      // Safe: last throttle implied consW >= nint-3 -> all loads retired.
      for (int c = NBB * (nint - 2) + q; c < TLEN; c += NPROD)
        *(float4*)(al + (size_t)c * LLEN + 4 * lane) = z4;
    }
  } else {
    // =================== consumers (barrier-free) ==========================
    auto pollC = [&](int X) {
      for (;;) {
        int m0 = 0 + 4 * *(volatile int*)&prodSb_s[0];
        int m1 = 1 + 4 * *(volatile int*)&prodSb_s[1];
        int m2 = 2 + 4 * *(volatile int*)&prodSb_s[2];
        int m3 = 3 + 4 * *(volatile int*)&prodSb_s[3];
        if (imin(imin(m0, m1), imin(m2, m3)) >= X) break;
        __builtin_amdgcn_s_sleep(1);
      }
      asm volatile("" ::: "memory");
    };
    auto publish = [&](int w1) {
      asm volatile("" ::: "memory");
      if (lane == 0) *(volatile int*)&consW_s = w1;
      asm volatile("" ::: "memory");
    };
    if (!is_beta) {
      // -------- forward logsumexp (f32, log2 domain) [R9 math] -------------
      float lp00 = lpb[0] * LOG2E_F;
      float o0 = (lane == 0) ? lp00 : NEGPADF;
      float o1 = NEGPADF, o2 = NEGPADF, o3 = NEGPADF;
      float f0 = o0, f1 = o1, f2 = o2, f3 = o3;
      float qv = rot1_f32(o3);
      pollC(imin(4, nsb));             // windows 0,1 staged
      float P[4][4];
      #pragma unroll
      for (int i = 0; i < 4; ++i) {    // prefetch window 0 steps 0..3
        const float* src = bufaF + i * 256;
        P[i][0] = src[lane]; P[i][1] = src[64 + lane];
        P[i][2] = src[128 + lane]; P[i][3] = src[192 + lane];
      }
      int t = 1;
      for (int w = 0; w < nint; ++w) {
        if (w) pollC(imin(2 * w + 4, nsb));
        int s = w % NBUF, sn = (w + 1) % NBUF;
        const float* baseS = bufaF + s * (NBB * 256);
        const float* baseN = bufaF + sn * (NBB * 256);
        #pragma unroll
        for (int j = 0; j < NBB; ++j, ++t) {
          int rj = j & 3;
          float l0 = P[rj][0], l1 = P[rj][1], l2 = P[rj][2], l3 = P[rj][3];
          const float* src = (j < NBB - 4) ? (baseS + (j + 4) * 256)
                                           : (baseN + (j + 4 - NBB) * 256);
          P[rj][0] = src[lane];       P[rj][1] = src[64 + lane];
          P[rj][2] = src[128 + lane]; P[rj][3] = src[192 + lane];
          float p = (lane == 0) ? NEGPADF : qv;
          float m0 = fmaxf(o0, p),  d0 = o0 - p;
          float m1 = fmaxf(o1, o0), d1 = o1 - o0;
          float m2 = fmaxf(o2, o1), d2 = o2 - o1;
          float m3 = fmaxf(o3, o2), d3 = o3 - o2;
          // log2(2^a+2^b) = max + log2(1 + 2^-|d|); 1e-7 pre-folded into l.
          float n0 = m0 + __builtin_amdgcn_logf(1.0f + __builtin_amdgcn_exp2f(-fabsf(d0))) + l0;
          float n1 = m1 + __builtin_amdgcn_logf(1.0f + __builtin_amdgcn_exp2f(-fabsf(d1))) + l1;
          float n2 = m2 + __builtin_amdgcn_logf(1.0f + __builtin_amdgcn_exp2f(-fabsf(d2))) + l2;
          float n3 = m3 + __builtin_amdgcn_logf(1.0f + __builtin_amdgcn_exp2f(-fabsf(d3))) + l3;
          o0 = n0; o1 = n1; o2 = n2; o3 = n3;
          qv = rot1_f32(o3);
          if (t == ml - 1) { f0 = o0; f1 = o1; f2 = o2; f3 = o3; }
        }
        publish(w + 1);
      }
      int fr = tl - 1;
      if (lane == (fr >> 2)) {
        int sx = fr & 3;
        float val = (sx == 0) ? f0 : (sx == 1) ? f1 : (sx == 2) ? f2 : f3;
        out[b] = -val * LN2_F / (float)ml;
      }
    } else {
      // -------- Viterbi max-DP (f64) [R9 math] -----------------------------
      double lp00 = (double)lpb[0] + (double)lob[0];
      double o0 = (lane == 0) ? lp00 : NEGPADD;
      double o1 = NEGPADD, o2 = NEGPADD, o3 = NEGPADD;
      uint32_t a0 = 0, a1 = (lane == 0) ? 1u : 0u, a2 = 0, a3 = 0;
      double qv = rot1_f64(o3);
      pollC(imin(4, nsb));             // windows 0,1 staged
      double P[4][4];
      #pragma unroll
      for (int i = 0; i < 4; ++i) {    // prefetch window 0 steps 0..3
        P[i][0] = bufd[0][i][0][lane]; P[i][1] = bufd[0][i][1][lane];
        P[i][2] = bufd[0][i][2][lane]; P[i][3] = bufd[0][i][3][lane];
      }
      int t = 1;
      for (int w = 0; w < nint; ++w) {
        if (w) pollC(imin(2 * w + 4, nsb));
        int s = w % NBUF, sn = (w + 1) % NBUF;
        const double (*bs)[4][64] = bufd[s];
        const double (*bn)[4][64] = bufd[sn];
        #pragma unroll
        for (int j = 0; j < NBB; ++j, ++t) {
          int rj = j & 3;
          double l0 = P[rj][0], l1 = P[rj][1], l2 = P[rj][2], l3 = P[rj][3];
          {
            const double (*src)[64] = (j < NBB - 4) ? bs[j + 4] : bn[j + 4 - NBB];
            P[rj][0] = src[0][lane]; P[rj][1] = src[1][lane];
            P[rj][2] = src[2][lane]; P[rj][3] = src[3][lane];
          }
          double p = (lane == 0) ? NEGPADD : qv;
          double n0 = fmax(o0, p)  + l0;
          double n1 = fmax(o1, o0) + l1;
          double n2 = fmax(o2, o1) + l2;
          double n3 = fmax(o3, o2) + l3;
          qv = rot1_f64(n3);                // row 4i-1 (mod 256) new beta
          uint32_t bit = 1u << (t & 31);
          if (qv > n0) a0 |= bit;
          if (n0 > n1) a1 |= bit;
          if (n1 > n2) a2 |= bit;
          if (n2 > n3) a3 |= bit;
          o0 = n0; o1 = n1; o2 = n2; o3 = n3;
          if ((t & 31) == 31) {
            int wd = t >> 5;
            Dbits[4 * lane + 0][wd] = a0; a0 = 0;
            Dbits[4 * lane + 1][wd] = a1; a1 = 0;
            Dbits[4 * lane + 2][wd] = a2; a2 = 0;
            Dbits[4 * lane + 3][wd] = a3; a3 = 0;
          }
        }
        publish(w + 1);
      }
      int tend = nint * NBB;             // last processed t
      int wd = tend >> 5;
      if ((tend & 31) != 31 && wd < TLEN / 32) {  // OOB guard (ml>=1594)
        Dbits[4 * lane + 0][wd] = a0;
        Dbits[4 * lane + 1][wd] = a1;
        Dbits[4 * lane + 2][wd] = a2;
        Dbits[4 * lane + 3][wd] = a3;
      }
      __builtin_amdgcn_s_waitcnt(WAIT_LGKM0);  // drain own-wave LDS ops

      // -------- literal backtrack [validated R2-R6] ------------------------
      if (lane == 0) {
        int r = tl - 1;
        pathL[ml - 1] = r;
        int curR = 1 << 30, curW = -1;
        uint32_t W = 0;
        for (int qq = ml - 2; qq >= 0; --qq) {
          int w2 = qq >> 5;
          if (r >= 0 && (r != curR || w2 != curW)) { W = Dbits[r][w2]; curR = r; curW = w2; }
          int g = (r >= 0) ? (int)((W >> (qq & 31)) & 1u) : 0;
          r -= g;
          pathL[qq] = r;
        }
      }
    }
  }

  // -------- fused finalize tail: scatter one-hots (beta blocks only) -------
  if (is_beta) {
    __syncthreads();                    // zero-fill + pathL complete
    for (int t = tid; t < ml; t += 320) {
      int p = pathL[t];
      if (p >= 0) al[(size_t)t * LLEN + p] = 1.0f;
    }
  }
}

extern "C" void kernel_launch(void* const* d_in, const int* in_sizes, int n_in,
                              void* d_out, int out_size, void* d_ws, size_t ws_size,
                              hipStream_t stream) {
  const float* mu_logvar = (const float*)d_in[0];
  const float* z         = (const float*)d_in[1];
  const int*   tlv       = (const int*)d_in[2];
  const int*   mlv       = (const int*)d_in[3];
  float* out = (float*)d_out;
  char*  wsb = (char*)d_ws;

  double* Ad   = (double*)(wsb + WSB_A);
  double* Kcd  = (double*)(wsb + WSB_KC);
  float*  lpTh = (float*)(wsb + WSB_LPT);

  prep_kernel<<<dim3(BB * LLEN / 4), 256, 0, stream>>>(mu_logvar, Ad, Kcd);
  lp_kernel<<<dim3(13, 8, BB), 128, 0, stream>>>(z, Ad, Kcd, out, lpTh);
  dp_kernel<<<dim3(2 * BB), 320, 0, stream>>>(lpTh, out, tlv, mlv, out);
}

// Round 7
// 549.859 us; speedup vs baseline: 1.0016x; 1.0016x over previous
//
#include <hip/hip_runtime.h>
#include <cstdint>
#include <math.h>

// Problem constants: B=32, TXT_T=256, MEL_T=1600, N_MEL=40
#define BB   32
#define LLEN 256
#define TLEN 1600
#define NC   40
#define NEGPADF (-1.0e12f)
#define NEGPADD (-1.0e12)

#define LOG2E_F 1.4426950408889634f
#define LN2_F   0.6931471805599453f
#define C7F     1.4426950408889634e-7f  // 1e-7*log2e, folded into alpha lp

// Output layout (floats): mdn_loss[32] | alignment[32*1600*256] | lp[32*256*1600]
#define OFF_ALIGN 32
#define OFF_LP    (32 + (size_t)BB * TLEN * LLEN)

// Workspace (bytes): Ad double[32*256*80] | Kcd double[32*256] | lpTh float[32*1600*256]
#define WSB_A    0
#define WSB_KC   (WSB_A + (size_t)BB * LLEN * 80 * 8)
#define WSB_LPT  (WSB_KC + (size_t)BB * LLEN * 8)

__device__ __forceinline__ int imin(int a, int b) { return a < b ? a : b; }

#define WAIT_LGKM0 0xC07F   // lgkmcnt(0) only                 [validated R2-R6]
#define WAIT_VM0   0x3F70   // vmcnt(0) only (lgkm=0x3F, exp=7 untouched)

// DPP wave-rotate-right-1: lane i <- lane i-1, lane 0 <- lane 63. VALU-only.
__device__ __forceinline__ int rot1_i32(int x) {
  return __builtin_amdgcn_mov_dpp(x, 0x13C /*wave_ror:1*/, 0xF, 0xF, true);
}
__device__ __forceinline__ float rot1_f32(float x) {
  return __int_as_float(rot1_i32(__float_as_int(x)));
}
__device__ __forceinline__ double rot1_f64(double x) {
  long long v = __double_as_longlong(x);
  int lo = rot1_i32((int)(v & 0xffffffffLL));
  int hi = rot1_i32((int)(v >> 32));
  return __longlong_as_double(((long long)hi << 32) | (unsigned long long)(unsigned int)lo);
}

// ---------------------------------------------------------------------------
// K0 (f64) [validated R2]
// ---------------------------------------------------------------------------
__global__ __launch_bounds__(256) void prep_kernel(
    const float* __restrict__ mu_logvar, double* __restrict__ A, double* __restrict__ Kc) {
  int row = blockIdx.x * 4 + (threadIdx.x >> 6);   // b*256 + l
  int lane = threadIdx.x & 63;
  const float* src = mu_logvar + (size_t)row * (2 * NC);
  double mu = 0.0, lv = 0.0, iv = 0.0, part = 0.0;
  if (lane < NC) {
    mu = (double)src[lane];
    lv = (double)src[NC + lane];
    iv = exp(-lv);
    part = mu * mu * iv + lv;
  }
  for (int m = 1; m < 64; m <<= 1) part += __shfl_xor(part, m, 64);
  const double s = -0.5 / (double)NC;
  if (lane < NC) {
    A[(size_t)row * 80 + lane]      = s * iv;
    A[(size_t)row * 80 + NC + lane] = (1.0 / (double)NC) * mu * iv;
  }
  if (lane == 0) Kc[row] = s * part;
}

// ---------------------------------------------------------------------------
// K1 (f64) [validated R2/R3/R5/R6 math]: lp + hi/lo transposed copies.
// ---------------------------------------------------------------------------
__global__ __launch_bounds__(128) void lp_kernel(
    const float* __restrict__ z, const double* __restrict__ A,
    const double* __restrict__ Kc, float* __restrict__ out,
    float* __restrict__ lpTh) {
  int b  = blockIdx.z;
  int l0 = blockIdx.y * 32;
  int t0 = blockIdx.x * 128;
  int tid = threadIdx.x;
  int t = t0 + tid;
  int tv = imin(t, TLEN - 1);
  bool act = (t < TLEN);

  float* lp_out = out + OFF_LP;
  float* loS    = out + OFF_ALIGN;   // lo scratch [b][t][l], zeroed by dp

  float zr[NC];
  const float* zb = z + (size_t)b * NC * TLEN;
  #pragma unroll
  for (int c = 0; c < NC; ++c) zr[c] = zb[(size_t)c * TLEN + tv];

  __shared__ __align__(16) double tile[128][17];
  const double* Ab = A + ((size_t)b * LLEN + l0) * 80;
  const double* Kb = Kc + (size_t)b * LLEN + l0;

  for (int g = 0; g < 2; ++g) {
    for (int j16 = 0; j16 < 16; ++j16) {
      int j = g * 16 + j16;
      const double* Ar = Ab + (size_t)j * 80;      // wave-uniform -> s_load
      double a0 = Kb[j], a1 = 0.0, a2 = 0.0, a3 = 0.0;
      #pragma unroll
      for (int c = 0; c < NC; c += 2) {
        double z0 = (double)zr[c], z1 = (double)zr[c + 1];
        a0 = fma(Ar[c],          z0 * z0, a0);
        a1 = fma(Ar[NC + c],     z0,      a1);
        a2 = fma(Ar[c + 1],      z1 * z1, a2);
        a3 = fma(Ar[NC + c + 1], z1,      a3);
      }
      double accd = (a0 + a2) + (a1 + a3);
      if (act) lp_out[((size_t)b * LLEN + l0 + j) * TLEN + t] = (float)accd;
      tile[tid][j16] = accd;
    }
    __syncthreads();
    #pragma unroll
    for (int p = 0; p < 4; ++p) {
      int idx = p * 128 + tid;
      int r = idx >> 2, c4 = idx & 3;
      int tr = t0 + r;
      if (tr < TLEN) {
        float h[4], lo[4];
        #pragma unroll
        for (int i = 0; i < 4; ++i) {
          double d = tile[r][c4 * 4 + i];
          float hh = (float)d;
          h[i] = hh;
          lo[i] = (float)(d - (double)hh);
        }
        size_t base = ((size_t)b * TLEN + tr) * LLEN + l0 + g * 16 + c4 * 4;
        *(float4*)(lpTh + base) = make_float4(h[0], h[1], h[2], h[3]);
        *(float4*)(loS + base)  = make_float4(lo[0], lo[1], lo[2], lo[3]);
      }
    }
    __syncthreads();
  }
}

// ---------------------------------------------------------------------------
// K2: DP. R14: ONE WAVE PER BLOCK. No producers, no LDS staging, no barriers,
// no flags, no spin -- nothing but the DP wave itself.
//  - Depth-8 global->register ring (global_load_dwordx4, 1KB/step coalesced,
//    L2/L3-resident data written by lp_kernel just before).
//  - Uniform 1600-step loop (kills the ml>=1594 tail-flush landmine); alpha
//    captures at t==ml-1; beta steps past ml produce bits never read back.
//  - beta self-zeroes the lo/alignment region: at step t it zeroes col t-8,
//    whose load was vmcnt-retired when consumed at step t-8 (same wave,
//    program order; out/outR carry NO __restrict__ since they alias, so the
//    compiler preserves load/store order). Tail zeroes col 0 + 1593..1599.
//    vmcnt(0) before the one-hot scatter so no zero lands after a 1.0.
//  - backtrack + scatter on the same wave (LDS ops per-wave are in-order;
//    explicit lgkmcnt(0) kept as validated insurance).
// Cross-block interactions: NONE (each block touches only its own b-slice).
// ---------------------------------------------------------------------------
__global__ __launch_bounds__(64, 1) void dp_kernel(
    const float* __restrict__ lpTh, const float* outR,
    const int* __restrict__ tlen, const int* __restrict__ mlen,
    float* out) {
  int bid = blockIdx.x;
  bool is_beta = (bid >= BB);
  int b = is_beta ? bid - BB : bid;
  int lane = threadIdx.x & 63;
  int tl = tlen[b];
  int ml = mlen[b];
  const float* lpb = lpTh + (size_t)b * TLEN * LLEN;
  const float* lob = outR + OFF_ALIGN + (size_t)b * TLEN * LLEN;
  float* al = out + OFF_ALIGN + (size_t)b * TLEN * LLEN;

  __shared__ uint32_t Dbits[LLEN][TLEN / 32];   // 51.2 KB (beta only)
  __shared__ int pathL[TLEN];                   // 6.4 KB

  const float* ph = lpb + 4 * lane;             // col c at ph + c*LLEN

  if (!is_beta) {
    // ================= alpha: forward logsumexp (f32, log2 domain) =========
    float lp00 = lpb[0] * LOG2E_F;
    float o0 = (lane == 0) ? lp00 : NEGPADF;
    float o1 = NEGPADF, o2 = NEGPADF, o3 = NEGPADF;
    float f0 = o0, f1 = o1, f2 = o2, f3 = o3;
    float qv = rot1_f32(o3);
    // ring prologue: cols 1..8 into slots 0..7
    float4 h0 = *(const float4*)(ph + 1 * LLEN);
    float4 h1 = *(const float4*)(ph + 2 * LLEN);
    float4 h2 = *(const float4*)(ph + 3 * LLEN);
    float4 h3 = *(const float4*)(ph + 4 * LLEN);
    float4 h4 = *(const float4*)(ph + 5 * LLEN);
    float4 h5 = *(const float4*)(ph + 6 * LLEN);
    float4 h6 = *(const float4*)(ph + 7 * LLEN);
    float4 h7 = *(const float4*)(ph + 8 * LLEN);
    int t = 1;
    auto stepA = [&](float4& hs) {
      float4 hv = hs;
      int c = imin(t + 8, TLEN - 1);
      hs = *(const float4*)(ph + (size_t)c * LLEN);   // refill (renamed reg)
      float l0 = fmaf(hv.x, LOG2E_F, C7F);
      float l1 = fmaf(hv.y, LOG2E_F, C7F);
      float l2 = fmaf(hv.z, LOG2E_F, C7F);
      float l3 = fmaf(hv.w, LOG2E_F, C7F);
      float p = (lane == 0) ? NEGPADF : qv;
      float m0 = fmaxf(o0, p),  d0 = o0 - p;
      float m1 = fmaxf(o1, o0), d1 = o1 - o0;
      float m2 = fmaxf(o2, o1), d2 = o2 - o1;
      float m3 = fmaxf(o3, o2), d3 = o3 - o2;
      // log2(2^a+2^b) = max + log2(1 + 2^-|d|); 1e-7 pre-folded into l.
      float n0 = m0 + __builtin_amdgcn_logf(1.0f + __builtin_amdgcn_exp2f(-fabsf(d0))) + l0;
      float n1 = m1 + __builtin_amdgcn_logf(1.0f + __builtin_amdgcn_exp2f(-fabsf(d1))) + l1;
      float n2 = m2 + __builtin_amdgcn_logf(1.0f + __builtin_amdgcn_exp2f(-fabsf(d2))) + l2;
      float n3 = m3 + __builtin_amdgcn_logf(1.0f + __builtin_amdgcn_exp2f(-fabsf(d3))) + l3;
      o0 = n0; o1 = n1; o2 = n2; o3 = n3;
      qv = rot1_f32(o3);
      if (t == ml - 1) { f0 = o0; f1 = o1; f2 = o2; f3 = o3; }
      ++t;
    };
    for (int tb = 0; tb < TLEN / 8; ++tb) {   // t = 1..1600
      stepA(h0); stepA(h1); stepA(h2); stepA(h3);
      stepA(h4); stepA(h5); stepA(h6); stepA(h7);
    }
    int fr = tl - 1;
    if (lane == (fr >> 2)) {
      int sx = fr & 3;
      float val = (sx == 0) ? f0 : (sx == 1) ? f1 : (sx == 2) ? f2 : f3;
      out[b] = -val * LN2_F / (float)ml;
    }
    return;
  }

  // ==================== beta: Viterbi max-DP (f64) ========================
  const float* pl = lob + 4 * lane;
  float* az = al + 4 * lane;
  float4 z4 = make_float4(0.f, 0.f, 0.f, 0.f);
  double lp00 = (double)lpb[0] + (double)lob[0];
  double o0 = (lane == 0) ? lp00 : NEGPADD;
  double o1 = NEGPADD, o2 = NEGPADD, o3 = NEGPADD;
  uint32_t a0 = 0, a1 = (lane == 0) ? 1u : 0u, a2 = 0, a3 = 0;
  double qv = rot1_f64(o3);
  // ring prologue: cols 1..8
  float4 h0 = *(const float4*)(ph + 1 * LLEN), g0 = *(const float4*)(pl + 1 * LLEN);
  float4 h1 = *(const float4*)(ph + 2 * LLEN), g1 = *(const float4*)(pl + 2 * LLEN);
  float4 h2 = *(const float4*)(ph + 3 * LLEN), g2 = *(const float4*)(pl + 3 * LLEN);
  float4 h3 = *(const float4*)(ph + 4 * LLEN), g3 = *(const float4*)(pl + 4 * LLEN);
  float4 h4 = *(const float4*)(ph + 5 * LLEN), g4 = *(const float4*)(pl + 5 * LLEN);
  float4 h5 = *(const float4*)(ph + 6 * LLEN), g5 = *(const float4*)(pl + 6 * LLEN);
  float4 h6 = *(const float4*)(ph + 7 * LLEN), g6 = *(const float4*)(pl + 7 * LLEN);
  float4 h7 = *(const float4*)(ph + 8 * LLEN), g7 = *(const float4*)(pl + 8 * LLEN);
  int t = 1;
  auto stepB = [&](float4& hs, float4& gs) {
    float4 hv = hs; float4 gv = gs;
    int c = imin(t + 8, TLEN - 1);
    hs = *(const float4*)(ph + (size_t)c * LLEN);
    gs = *(const float4*)(pl + (size_t)c * LLEN);
    double l0 = (double)hv.x + (double)gv.x;
    double l1 = (double)hv.y + (double)gv.y;
    double l2 = (double)hv.z + (double)gv.z;
    double l3 = (double)hv.w + (double)gv.w;
    double p = (lane == 0) ? NEGPADD : qv;
    double n0 = fmax(o0, p)  + l0;
    double n1 = fmax(o1, o0) + l1;
    double n2 = fmax(o2, o1) + l2;
    double n3 = fmax(o3, o2) + l3;
    qv = rot1_f64(n3);                // row 4i-1 (mod 256) new beta
    uint32_t bit = 1u << (t & 31);
    if (qv > n0) a0 |= bit;
    if (n0 > n1) a1 |= bit;
    if (n1 > n2) a2 |= bit;
    if (n2 > n3) a3 |= bit;
    o0 = n0; o1 = n1; o2 = n2; o3 = n3;
    if ((t & 31) == 31) {
      int wd = t >> 5;
      Dbits[4 * lane + 0][wd] = a0; a0 = 0;
      Dbits[4 * lane + 1][wd] = a1; a1 = 0;
      Dbits[4 * lane + 2][wd] = a2; a2 = 0;
      Dbits[4 * lane + 3][wd] = a3; a3 = 0;
    }
    // self-zero col t-8: consumed (and vmcnt-retired) 8 steps ago.
    if (t > 8) *(float4*)(az + (size_t)(t - 8) * LLEN) = z4;
    ++t;
  };
  for (int tb = 0; tb < TLEN / 8; ++tb) {   // t = 1..1600; flush @ t=31..1599
    stepB(h0, g0); stepB(h1, g1); stepB(h2, g2); stepB(h3, g3);
    stepB(h4, g4); stepB(h5, g5); stepB(h6, g6); stepB(h7, g7);
  }
  // tail zero: col 0 (lp00 long consumed) + cols 1593..1599.
  *(float4*)az = z4;
  #pragma unroll
  for (int c = TLEN - 7; c < TLEN; ++c)
    *(float4*)(az + (size_t)c * LLEN) = z4;

  __builtin_amdgcn_s_waitcnt(WAIT_LGKM0);  // drain own-wave Dbits writes

  // -------- literal backtrack [validated R2-R6] ---------------------------
  if (lane == 0) {
    int r = tl - 1;
    pathL[ml - 1] = r;
    int curR = 1 << 30, curW = -1;
    uint32_t W = 0;
    for (int qq = ml - 2; qq >= 0; --qq) {
      int w2 = qq >> 5;
      if (r >= 0 && (r != curR || w2 != curW)) { W = Dbits[r][w2]; curR = r; curW = w2; }
      int g = (r >= 0) ? (int)((W >> (qq & 31)) & 1u) : 0;
      r -= g;
      pathL[qq] = r;
    }
  }
  __builtin_amdgcn_s_waitcnt(WAIT_LGKM0);  // pathL visible to all lanes
  __builtin_amdgcn_s_waitcnt(WAIT_VM0);    // all zero-stores retired

  // -------- scatter one-hots (same wave) ----------------------------------
  for (int tt = lane; tt < ml; tt += 64) {
    int p = pathL[tt];
    if (p >= 0) al[(size_t)tt * LLEN + p] = 1.0f;
  }
}

extern "C" void kernel_launch(void* const* d_in, const int* in_sizes, int n_in,
                              void* d_out, int out_size, void* d_ws, size_t ws_size,
                              hipStream_t stream) {
  const float* mu_logvar = (const float*)d_in[0];
  const float* z         = (const float*)d_in[1];
  const int*   tlv       = (const int*)d_in[2];
  const int*   mlv       = (const int*)d_in[3];
  float* out = (float*)d_out;
  char*  wsb = (char*)d_ws;

  double* Ad   = (double*)(wsb + WSB_A);
  double* Kcd  = (double*)(wsb + WSB_KC);
  float*  lpTh = (float*)(wsb + WSB_LPT);

  prep_kernel<<<dim3(BB * LLEN / 4), 256, 0, stream>>>(mu_logvar, Ad, Kcd);
  lp_kernel<<<dim3(13, 8, BB), 128, 0, stream>>>(z, Ad, Kcd, out, lpTh);
  dp_kernel<<<dim3(2 * BB), 64, 0, stream>>>(lpTh, out, tlv, mlv, out);
}

// Round 9
// 527.345 us; speedup vs baseline: 1.0444x; 1.0427x over previous
//
#include <hip/hip_runtime.h>
#include <cstdint>
#include <math.h>

// Problem constants: B=32, TXT_T=256, MEL_T=1600, N_MEL=40
#define BB   32
#define LLEN 256
#define TLEN 1600
#define NC   40
#define NEGPADF (-1.0e12f)
#define NEGPADD (-1.0e12)

#define LOG2E_F 1.4426950408889634f
#define LN2_F   0.6931471805599453f
#define C7F     1.4426950408889634e-7f  // 1e-7*log2e, folded into alpha lp
// log2(1+y) ~= y*(PA + y*(PB + y*PC)) on y in (0,1]; max err ~4e-3
#define PA_F 1.4426950f
#define PB_F (-0.6484000f)
#define PC_F 0.2057000f

// Output layout (floats): mdn_loss[32] | alignment[32*1600*256] | lp[32*256*1600]
#define OFF_ALIGN 32
#define OFF_LP    (32 + (size_t)BB * TLEN * LLEN)

// Workspace (bytes): Ad double[32*256*80] | Kcd double[32*256] | bufA[52.4MB]
#define WSB_A    0
#define WSB_KC   (WSB_A + (size_t)BB * LLEN * 80 * 8)
#define WSB_LPT  (WSB_KC + (size_t)BB * LLEN * 8)

__device__ __forceinline__ int imin(int a, int b) { return a < b ? a : b; }

#define WAIT_LGKM0 0xC07F   // lgkmcnt(0) only                 [validated R2-R6]
#define WAIT_VM0   0x3F70   // vmcnt(0) only

// DPP wave-rotate-right-1: lane i <- lane i-1, lane 0 <- lane 63. VALU-only.
__device__ __forceinline__ int rot1_i32(int x) {
  return __builtin_amdgcn_mov_dpp(x, 0x13C /*wave_ror:1*/, 0xF, 0xF, true);
}
__device__ __forceinline__ float rot1_f32(float x) {
  return __int_as_float(rot1_i32(__float_as_int(x)));
}
__device__ __forceinline__ double rot1_f64(double x) {
  long long v = __double_as_longlong(x);
  int lo = rot1_i32((int)(v & 0xffffffffLL));
  int hi = rot1_i32((int)(v >> 32));
  return __longlong_as_double(((long long)hi << 32) | (unsigned long long)(unsigned int)lo);
}

// ---------------------------------------------------------------------------
// K0 (f64) [validated R2]
// ---------------------------------------------------------------------------
__global__ __launch_bounds__(256) void prep_kernel(
    const float* __restrict__ mu_logvar, double* __restrict__ A, double* __restrict__ Kc) {
  int row = blockIdx.x * 4 + (threadIdx.x >> 6);   // b*256 + l
  int lane = threadIdx.x & 63;
  const float* src = mu_logvar + (size_t)row * (2 * NC);
  double mu = 0.0, lv = 0.0, iv = 0.0, part = 0.0;
  if (lane < NC) {
    mu = (double)src[lane];
    lv = (double)src[NC + lane];
    iv = exp(-lv);
    part = mu * mu * iv + lv;
  }
  for (int m = 1; m < 64; m <<= 1) part += __shfl_xor(part, m, 64);
  const double s = -0.5 / (double)NC;
  if (lane < NC) {
    A[(size_t)row * 80 + lane]      = s * iv;
    A[(size_t)row * 80 + NC + lane] = (1.0 / (double)NC) * mu * iv;
  }
  if (lane == 0) Kc[row] = s * part;
}

// ---------------------------------------------------------------------------
// K1 (f64) [validated R2/R3/R5/R6 math]. Staging: raw f64 bit-pairs:
//   bufA[(b*1600+t)*64 + lane] = {d(4*lane), d(4*lane+1)}   (double2, 16B, WS)
//   bufB[(b*1600+t)*64 + lane] = {d(4*lane+2), d(4*lane+3)} (alignment region)
// RACE RULE [R15 bug]: the alignment region (bufB) is zeroed DURING the beta
// DP, so ONLY beta block b may read bufB[b]. Alpha reads bufA (WS, safe) and
// the lp output (read-only after lp_kernel).
// ---------------------------------------------------------------------------
__global__ __launch_bounds__(128) void lp_kernel(
    const float* __restrict__ z, const double* __restrict__ A,
    const double* __restrict__ Kc, float* out,
    float* __restrict__ lpTh) {
  int b  = blockIdx.z;
  int l0 = blockIdx.y * 32;
  int t0 = blockIdx.x * 128;
  int tid = threadIdx.x;
  int t = t0 + tid;
  int tv = imin(t, TLEN - 1);
  bool act = (t < TLEN);

  float* lp_out = out + OFF_LP;
  double2* bufA = (double2*)lpTh;
  double2* bufB = (double2*)(out + OFF_ALIGN);

  float zr[NC];
  const float* zb = z + (size_t)b * NC * TLEN;
  #pragma unroll
  for (int c = 0; c < NC; ++c) zr[c] = zb[(size_t)c * TLEN + tv];

  __shared__ __align__(16) double tile[128][17];
  const double* Ab = A + ((size_t)b * LLEN + l0) * 80;
  const double* Kb = Kc + (size_t)b * LLEN + l0;

  for (int g = 0; g < 2; ++g) {
    for (int j16 = 0; j16 < 16; ++j16) {
      int j = g * 16 + j16;
      const double* Ar = Ab + (size_t)j * 80;      // wave-uniform -> s_load
      double a0 = Kb[j], a1 = 0.0, a2 = 0.0, a3 = 0.0;
      #pragma unroll
      for (int c = 0; c < NC; c += 2) {
        double z0 = (double)zr[c], z1 = (double)zr[c + 1];
        a0 = fma(Ar[c],          z0 * z0, a0);
        a1 = fma(Ar[NC + c],     z0,      a1);
        a2 = fma(Ar[c + 1],      z1 * z1, a2);
        a3 = fma(Ar[NC + c + 1], z1,      a3);
      }
      double accd = (a0 + a2) + (a1 + a3);
      if (act) lp_out[((size_t)b * LLEN + l0 + j) * TLEN + t] = (float)accd;
      tile[tid][j16] = accd;
    }
    __syncthreads();
    #pragma unroll
    for (int p = 0; p < 4; ++p) {
      int idx = p * 128 + tid;
      int r = idx >> 2, c4 = idx & 3;
      int tr = t0 + r;
      if (tr < TLEN) {
        size_t chunk = ((size_t)b * TLEN + tr) * 64 + (l0 + g * 16) / 4 + c4;
        double2 dA, dB;
        dA.x = tile[r][c4 * 4 + 0]; dA.y = tile[r][c4 * 4 + 1];
        dB.x = tile[r][c4 * 4 + 2]; dB.y = tile[r][c4 * 4 + 3];
        bufA[chunk] = dA;
        bufB[chunk] = dB;
      }
    }
    __syncthreads();
  }
}

// ---------------------------------------------------------------------------
// K2: DP. R16 = R15 skeleton with the cross-block race FIXED:
//  - alpha sources: {d0,d1} from bufA (workspace, never zeroed) + {d2,d3} as
//    f32 directly from the lp output [b][l][t] (saddr-form gather, values
//    bit-identical to the old staged f32-hi). Alpha never touches bufB.
//  - alpha softplus: log2(1+2^-|d|) ~= y*(PA+y*(PB+y*PC)), y=exp2(-|d|).
//    4 trans/step instead of 8; loss-error budget <= 0.006 vs 0.45 threshold.
//  - beta: unchanged R15 (f64 pairs zero-reconstruction, cmp+addc MSB bits,
//    self-zero col t-8, uniform 1600-step loop, backtrack bit 31-(qq&31)).
// ---------------------------------------------------------------------------
__global__ __launch_bounds__(64, 1) void dp_kernel(
    const float* __restrict__ lpTh, const float* outR,
    const int* __restrict__ tlen, const int* __restrict__ mlen,
    float* out) {
  int bid = blockIdx.x;
  bool is_beta = (bid >= BB);
  int b = is_beta ? bid - BB : bid;
  int lane = threadIdx.x & 63;
  int tl = tlen[b];
  int ml = mlen[b];
  const double2* pA = (const double2*)lpTh + (size_t)b * TLEN * 64;
  const double2* pB = (const double2*)(outR + OFF_ALIGN) + (size_t)b * TLEN * 64;
  float* al = out + OFF_ALIGN + (size_t)b * TLEN * LLEN;

  __shared__ uint32_t Dbits[LLEN][TLEN / 32];   // 51.2 KB (beta only)
  __shared__ int pathL[TLEN];                   // 6.4 KB

  if (!is_beta) {
    // ================= alpha: forward logsumexp (f32, log2 domain) =========
    const float* gB = outR + OFF_LP + (size_t)b * LLEN * TLEN;  // lp [l][t]
    int off2 = (4 * lane + 2) * TLEN;
    int off3 = off2 + TLEN;
    double2 v00 = pA[lane];                      // lane0.x = lp(l=0, t=0)
    float lp00 = (float)v00.x * LOG2E_F;
    float o0 = (lane == 0) ? lp00 : NEGPADF;
    float o1 = NEGPADF, o2 = NEGPADF, o3 = NEGPADF;
    float f0 = o0, f1 = o1, f2 = o2, f3 = o3;
    float qv = rot1_f32(o3);
    // ring prologue: cols 1..8
    double2 hA0, hA1, hA2, hA3, hA4, hA5, hA6, hA7;
    float r20, r21, r22, r23, r24, r25, r26, r27;
    float r30, r31, r32, r33, r34, r35, r36, r37;
    hA0 = pA[1 * 64 + lane]; { const float* bt = gB + 1; r20 = bt[off2]; r30 = bt[off3]; }
    hA1 = pA[2 * 64 + lane]; { const float* bt = gB + 2; r21 = bt[off2]; r31 = bt[off3]; }
    hA2 = pA[3 * 64 + lane]; { const float* bt = gB + 3; r22 = bt[off2]; r32 = bt[off3]; }
    hA3 = pA[4 * 64 + lane]; { const float* bt = gB + 4; r23 = bt[off2]; r33 = bt[off3]; }
    hA4 = pA[5 * 64 + lane]; { const float* bt = gB + 5; r24 = bt[off2]; r34 = bt[off3]; }
    hA5 = pA[6 * 64 + lane]; { const float* bt = gB + 6; r25 = bt[off2]; r35 = bt[off3]; }
    hA6 = pA[7 * 64 + lane]; { const float* bt = gB + 7; r26 = bt[off2]; r36 = bt[off3]; }
    hA7 = pA[8 * 64 + lane]; { const float* bt = gB + 8; r27 = bt[off2]; r37 = bt[off3]; }
    int t = 1;
    auto stepA = [&](double2& ha, float& r2, float& r3) {
      float v0 = (float)ha.x, v1 = (float)ha.y;
      float v2 = r2, v3 = r3;
      int c = imin(t + 8, TLEN - 1);
      ha = (pA + (size_t)c * 64)[lane];
      { const float* bt = gB + c; r2 = bt[off2]; r3 = bt[off3]; }
      float l0 = fmaf(v0, LOG2E_F, C7F);
      float l1 = fmaf(v1, LOG2E_F, C7F);
      float l2 = fmaf(v2, LOG2E_F, C7F);
      float l3 = fmaf(v3, LOG2E_F, C7F);
      float p = (lane == 0) ? NEGPADF : qv;
      float m0 = fmaxf(o0, p),  d0 = fabsf(o0 - p);
      float m1 = fmaxf(o1, o0), d1 = fabsf(o1 - o0);
      float m2 = fmaxf(o2, o1), d2 = fabsf(o2 - o1);
      float m3 = fmaxf(o3, o2), d3 = fabsf(o3 - o2);
      float y0 = __builtin_amdgcn_exp2f(-d0);
      float y1 = __builtin_amdgcn_exp2f(-d1);
      float y2 = __builtin_amdgcn_exp2f(-d2);
      float y3 = __builtin_amdgcn_exp2f(-d3);
      float s0 = y0 * fmaf(y0, fmaf(y0, PC_F, PB_F), PA_F);
      float s1 = y1 * fmaf(y1, fmaf(y1, PC_F, PB_F), PA_F);
      float s2 = y2 * fmaf(y2, fmaf(y2, PC_F, PB_F), PA_F);
      float s3 = y3 * fmaf(y3, fmaf(y3, PC_F, PB_F), PA_F);
      float n0 = m0 + s0 + l0;
      float n1 = m1 + s1 + l1;
      float n2 = m2 + s2 + l2;
      float n3 = m3 + s3 + l3;
      o0 = n0; o1 = n1; o2 = n2; o3 = n3;
      qv = rot1_f32(o3);
      if (t == ml - 1) { f0 = o0; f1 = o1; f2 = o2; f3 = o3; }
      ++t;
    };
    for (int tb = 0; tb < TLEN / 8; ++tb) {   // t = 1..1600
      stepA(hA0, r20, r30); stepA(hA1, r21, r31);
      stepA(hA2, r22, r32); stepA(hA3, r23, r33);
      stepA(hA4, r24, r34); stepA(hA5, r25, r35);
      stepA(hA6, r26, r36); stepA(hA7, r27, r37);
    }
    int fr = tl - 1;
    if (lane == (fr >> 2)) {
      int sx = fr & 3;
      float val = (sx == 0) ? f0 : (sx == 1) ? f1 : (sx == 2) ? f2 : f3;
      out[b] = -val * LN2_F / (float)ml;
    }
    return;
  }

  // ==================== beta: Viterbi max-DP (f64) [R15 structure] ========
  float4 z4 = make_float4(0.f, 0.f, 0.f, 0.f);
  double2 v00 = pA[lane];                       // lane0.x = lp(l=0, t=0)
  double lp00 = v00.x;
  double o0 = (lane == 0) ? lp00 : NEGPADD;
  double o1 = NEGPADD, o2 = NEGPADD, o3 = NEGPADD;
  // shift-accumulate decision words (MSB-first); a1 seed = t=0 decision.
  uint32_t a0 = 0, a1 = (lane == 0) ? 1u : 0u, a2 = 0, a3 = 0;
  double qv = rot1_f64(o3);
  // ring prologue: cols 1..8
  double2 hA0 = pA[1 * 64 + lane], hB0 = pB[1 * 64 + lane];
  double2 hA1 = pA[2 * 64 + lane], hB1 = pB[2 * 64 + lane];
  double2 hA2 = pA[3 * 64 + lane], hB2 = pB[3 * 64 + lane];
  double2 hA3 = pA[4 * 64 + lane], hB3 = pB[4 * 64 + lane];
  double2 hA4 = pA[5 * 64 + lane], hB4 = pB[5 * 64 + lane];
  double2 hA5 = pA[6 * 64 + lane], hB5 = pB[6 * 64 + lane];
  double2 hA6 = pA[7 * 64 + lane], hB6 = pB[7 * 64 + lane];
  double2 hA7 = pA[8 * 64 + lane], hB7 = pB[8 * 64 + lane];
  int t = 1;
  auto stepB = [&](double2& ha, double2& hb) {
    double l0 = ha.x, l1 = ha.y, l2 = hb.x, l3 = hb.y;
    int c = imin(t + 8, TLEN - 1);
    ha = (pA + (size_t)c * 64)[lane];
    hb = (pB + (size_t)c * 64)[lane];
    double p = (lane == 0) ? NEGPADD : qv;
    double n0 = fmax(o0, p)  + l0;
    double n1 = fmax(o1, o0) + l1;
    double n2 = fmax(o2, o1) + l2;
    double n3 = fmax(o3, o2) + l3;
    qv = rot1_f64(n3);                // row 4i-1 (mod 256) new beta
    // a = (a<<1) | (x>y)  via cmp -> vcc -> addc (2 insts/row)
    asm("v_cmp_gt_f64 vcc, %1, %2\n\t"
        "v_addc_co_u32 %0, vcc, %0, %0, vcc"
        : "+v"(a0) : "v"(qv), "v"(n0) : "vcc");
    asm("v_cmp_gt_f64 vcc, %1, %2\n\t"
        "v_addc_co_u32 %0, vcc, %0, %0, vcc"
        : "+v"(a1) : "v"(n0), "v"(n1) : "vcc");
    asm("v_cmp_gt_f64 vcc, %1, %2\n\t"
        "v_addc_co_u32 %0, vcc, %0, %0, vcc"
        : "+v"(a2) : "v"(n1), "v"(n2) : "vcc");
    asm("v_cmp_gt_f64 vcc, %1, %2\n\t"
        "v_addc_co_u32 %0, vcc, %0, %0, vcc"
        : "+v"(a3) : "v"(n2), "v"(n3) : "vcc");
    o0 = n0; o1 = n1; o2 = n2; o3 = n3;
    if ((t & 31) == 31) {
      int wd = t >> 5;
      Dbits[4 * lane + 0][wd] = a0; a0 = 0;
      Dbits[4 * lane + 1][wd] = a1; a1 = 0;
      Dbits[4 * lane + 2][wd] = a2; a2 = 0;
      Dbits[4 * lane + 3][wd] = a3; a3 = 0;
    }
    // self-zero col t-8 of the alignment region (load consumed 8 steps ago).
    if (t > 8) ((float4*)(al + (size_t)(t - 8) * LLEN))[lane] = z4;
    ++t;
  };
  for (int tb = 0; tb < TLEN / 8; ++tb) {   // t = 1..1600; flush @ 31..1599
    stepB(hA0, hB0); stepB(hA1, hB1); stepB(hA2, hB2); stepB(hA3, hB3);
    stepB(hA4, hB4); stepB(hA5, hB5); stepB(hA6, hB6); stepB(hA7, hB7);
  }
  // tail zero: col 0 + cols 1593..1599.
  ((float4*)al)[lane] = z4;
  #pragma unroll
  for (int c = TLEN - 7; c < TLEN; ++c)
    ((float4*)(al + (size_t)c * LLEN))[lane] = z4;

  __builtin_amdgcn_s_waitcnt(WAIT_LGKM0);  // drain own-wave Dbits writes

  // -------- literal backtrack [validated R2-R6], MSB-first bits -----------
  if (lane == 0) {
    int r = tl - 1;
    pathL[ml - 1] = r;
    int curR = 1 << 30, curW = -1;
    uint32_t W = 0;
    for (int qq = ml - 2; qq >= 0; --qq) {
      int w2 = qq >> 5;
      if (r >= 0 && (r != curR || w2 != curW)) { W = Dbits[r][w2]; curR = r; curW = w2; }
      int g = (r >= 0) ? (int)((W >> (31 - (qq & 31))) & 1u) : 0;
      r -= g;
      pathL[qq] = r;
    }
  }
  __builtin_amdgcn_s_waitcnt(WAIT_LGKM0);  // pathL visible to all lanes
  __builtin_amdgcn_s_waitcnt(WAIT_VM0);    // all zero-stores retired

  // -------- scatter one-hots (same wave) ----------------------------------
  for (int tt = lane; tt < ml; tt += 64) {
    int p = pathL[tt];
    if (p >= 0) al[(size_t)tt * LLEN + p] = 1.0f;
  }
}

extern "C" void kernel_launch(void* const* d_in, const int* in_sizes, int n_in,
                              void* d_out, int out_size, void* d_ws, size_t ws_size,
                              hipStream_t stream) {
  const float* mu_logvar = (const float*)d_in[0];
  const float* z         = (const float*)d_in[1];
  const int*   tlv       = (const int*)d_in[2];
  const int*   mlv       = (const int*)d_in[3];
  float* out = (float*)d_out;
  char*  wsb = (char*)d_ws;

  double* Ad   = (double*)(wsb + WSB_A);
  double* Kcd  = (double*)(wsb + WSB_KC);
  float*  lpTh = (float*)(wsb + WSB_LPT);

  prep_kernel<<<dim3(BB * LLEN / 4), 256, 0, stream>>>(mu_logvar, Ad, Kcd);
  lp_kernel<<<dim3(13, 8, BB), 128, 0, stream>>>(z, Ad, Kcd, out, lpTh);
  dp_kernel<<<dim3(2 * BB), 64, 0, stream>>>(lpTh, out, tlv, mlv, out);
}